// Round 1
// baseline (3804.939 us; speedup 1.0000x reference)
//
#include <hip/hip_runtime.h>
#include <hip/hip_bf16.h>
#include <cstdint>
#include <cstddef>

#define BATCH 4096
#define DIM   2048
#define FEAT  16384

typedef __attribute__((ext_vector_type(8))) short s8v;
typedef __attribute__((ext_vector_type(4))) float f4v;

__device__ __forceinline__ unsigned short f2bf(float f){
  unsigned u = __float_as_uint(f);
  unsigned r = u + 0x7FFFu + ((u >> 16) & 1u);
  return (unsigned short)(r >> 16);
}
__device__ __forceinline__ float bf2f(unsigned short h){
  return __uint_as_float(((unsigned)h) << 16);
}
__device__ __forceinline__ void split3(float v, unsigned short &h, unsigned short &m, unsigned short &l){
  h = f2bf(v);
  float r1 = v - bf2f(h);
  m = f2bf(r1);
  float r2 = r1 - bf2f(m);
  l = f2bf(r2);
}

// ---------------------------------------------------------------------------
// GEMM with on-the-fly 3-way bf16 split, 6 MFMA products (fp32-equivalent).
// C[row, col] = (X[row,:] - bsub[:]) dot W[col,:]
// MODE 0: acts[row*FEAT+col] = relu(C + bias[col])
// MODE 1: h = relu(C + bias[col]); zpart[row*256 + colblk] = sum_h(h * w2[col])
// ---------------------------------------------------------------------------
template<int MODE>
__global__ __launch_bounds__(256)
void gemm6(const float* __restrict__ X, const float* __restrict__ bsub,
           const float* __restrict__ W, const float* __restrict__ bias,
           const float* __restrict__ w2, float* __restrict__ acts,
           float* __restrict__ zpart)
{
  __shared__ unsigned short sA[3][128][32];
  __shared__ unsigned short sB[3][128][32];
  const int tid  = threadIdx.x;
  const int row0 = blockIdx.y << 7;
  const int col0 = blockIdx.x << 7;
  const int lane = tid & 63, wv = tid >> 6;
  const int wr = (wv & 1) << 6, wc = (wv >> 1) << 6;
  const int fr = lane & 15;
  const int gsw = (((lane >> 4) ^ ((fr >> 1) & 3)) << 3);  // swizzled k-group byte-col

  f4v acc[4][4];
  #pragma unroll
  for (int i = 0; i < 4; ++i)
    #pragma unroll
    for (int j = 0; j < 4; ++j)
      acc[i][j] = (f4v){0.f, 0.f, 0.f, 0.f};

  const int rs = tid >> 3;          // row-within-32 for staging
  const int cb = (tid & 7) << 2;    // col 0,4,...,28
  const int gq = cb >> 3;           // 16B group index of this 4-col chunk

  for (int kt = 0; kt < DIM / 32; ++kt){
    const int k0 = kt << 5;
    #pragma unroll
    for (int i = 0; i < 4; ++i){
      const int r  = (i << 5) + rs;
      const int cs = ((gq ^ ((r >> 1) & 3)) << 3) + (cb & 7);
      {
        const float4 xv = *(const float4*)(X + (size_t)(row0 + r) * DIM + k0 + cb);
        const float4 bd = *(const float4*)(bsub + k0 + cb);
        float v0 = xv.x - bd.x, v1 = xv.y - bd.y, v2 = xv.z - bd.z, v3 = xv.w - bd.w;
        ushort4 H, M, L;
        split3(v0, H.x, M.x, L.x); split3(v1, H.y, M.y, L.y);
        split3(v2, H.z, M.z, L.z); split3(v3, H.w, M.w, L.w);
        *(ushort4*)&sA[0][r][cs] = H;
        *(ushort4*)&sA[1][r][cs] = M;
        *(ushort4*)&sA[2][r][cs] = L;
      }
      {
        const float4 wv4 = *(const float4*)(W + (size_t)(col0 + r) * DIM + k0 + cb);
        ushort4 H, M, L;
        split3(wv4.x, H.x, M.x, L.x); split3(wv4.y, H.y, M.y, L.y);
        split3(wv4.z, H.z, M.z, L.z); split3(wv4.w, H.w, M.w, L.w);
        *(ushort4*)&sB[0][r][cs] = H;
        *(ushort4*)&sB[1][r][cs] = M;
        *(ushort4*)&sB[2][r][cs] = L;
      }
    }
    __syncthreads();
    #pragma unroll
    for (int pa = 0; pa < 3; ++pa){
      s8v a[4];
      #pragma unroll
      for (int fi = 0; fi < 4; ++fi)
        a[fi] = *(const s8v*)&sA[pa][wr + (fi << 4) + fr][gsw];
      #pragma unroll
      for (int pb = 0; pb < 3 - pa; ++pb){
        s8v b[4];
        #pragma unroll
        for (int fj = 0; fj < 4; ++fj)
          b[fj] = *(const s8v*)&sB[pb][wc + (fj << 4) + fr][gsw];
        #pragma unroll
        for (int fi = 0; fi < 4; ++fi)
          #pragma unroll
          for (int fj = 0; fj < 4; ++fj)
            acc[fi][fj] = __builtin_amdgcn_mfma_f32_16x16x32_bf16(a[fi], b[fj], acc[fi][fj], 0, 0, 0);
      }
    }
    __syncthreads();
  }

  const int rq = (lane >> 4) << 2;
  if (MODE == 0){
    #pragma unroll
    for (int fj = 0; fj < 4; ++fj){
      const int gcol = col0 + wc + (fj << 4) + fr;
      const float be = bias[gcol];
      #pragma unroll
      for (int fi = 0; fi < 4; ++fi){
        #pragma unroll
        for (int r = 0; r < 4; ++r){
          const int grow = row0 + wr + (fi << 4) + rq + r;
          float v = acc[fi][fj][r] + be;
          v = fmaxf(v, 0.f);
          acts[(size_t)grow * FEAT + gcol] = v;
        }
      }
    }
  } else {
    float be[4], wk[4];
    #pragma unroll
    for (int fj = 0; fj < 4; ++fj){
      const int gcol = col0 + wc + (fj << 4) + fr;
      be[fj] = bias[gcol];
      wk[fj] = w2[gcol];
    }
    #pragma unroll
    for (int fi = 0; fi < 4; ++fi){
      #pragma unroll
      for (int r = 0; r < 4; ++r){
        float s = 0.f;
        #pragma unroll
        for (int fj = 0; fj < 4; ++fj){
          float h = fmaxf(acc[fi][fj][r] + be[fj], 0.f);
          s = fmaf(h, wk[fj], s);
        }
        s += __shfl_xor(s, 1);
        s += __shfl_xor(s, 2);
        s += __shfl_xor(s, 4);
        s += __shfl_xor(s, 8);
        if (fr == 0){
          const int grow = row0 + wr + (fi << 4) + rq + r;
          zpart[(size_t)grow * 256 + (blockIdx.x << 1) + (wc >> 6)] = s;
        }
      }
    }
  }
}

// ---------------------------------------------------------------------------
// z reduce -> k_est -> m = ceil(k_est). 4 rows per block, 64 lanes per row.
// ---------------------------------------------------------------------------
__global__ __launch_bounds__(256)
void zreduce(const float* __restrict__ zpart, const float* __restrict__ bk2,
             const int* __restrict__ kp, int* __restrict__ mrow)
{
  const int row  = blockIdx.x * 4 + (threadIdx.x >> 6);
  const int lane = threadIdx.x & 63;
  const float* zp = zpart + (size_t)row * 256;
  float s = zp[lane] + zp[lane + 64] + zp[lane + 128] + zp[lane + 192];
  s += __shfl_xor(s, 1);
  s += __shfl_xor(s, 2);
  s += __shfl_xor(s, 4);
  s += __shfl_xor(s, 8);
  s += __shfl_xor(s, 16);
  s += __shfl_xor(s, 32);
  if (lane == 0){
    float z = s + bk2[0];
    float kest = 2.f * (float)(*kp) * (1.f / (1.f + expf(-z)));
    int m = (int)ceilf(kest);
    m = min(max(m, 0), 128);
    mrow[row] = m;
  }
}

// ---------------------------------------------------------------------------
// Radix select helpers
// ---------------------------------------------------------------------------
__device__ __forceinline__ void radix_find(int* hist, int nbins, int need, int tid,
                                           int* out3, int* blksum)
{
  const int per  = nbins >> 8;
  const int base = tid * per;
  int bs = 0;
  for (int j = 0; j < per; ++j) bs += hist[base + j];
  blksum[tid] = bs;
  __syncthreads();
  if (tid == 0){
    int a2 = 0;
    for (int t = 255; t >= 0; --t){ int v = blksum[t]; blksum[t] = a2; a2 += v; }
  }
  __syncthreads();
  int ch = blksum[tid];   // count of elements in bins strictly above current
  for (int j = per - 1; j >= 0; --j){
    const int b = base + j;
    const int c = hist[b];
    if (ch < need && need <= ch + c){ out3[0] = b; out3[1] = need - ch; out3[2] = ch; }
    ch += c;
  }
  __syncthreads();
}

// Per-row exact top-m selection: 3-pass radix (11/11/10 bits) on the float
// bit pattern (all acts >= 0 -> monotone), then deterministic index-ordered
// compaction (matches numpy's stable argsort tie behavior).
__global__ __launch_bounds__(256)
void select_topk(const float* __restrict__ acts, const int* __restrict__ mrow,
                 int* __restrict__ selIdx, float* __restrict__ selVal)
{
  __shared__ int hist[2048];
  __shared__ int blksum[256];
  __shared__ int out3[4];
  __shared__ unsigned listU[2048];
  __shared__ int lcnt;

  const int row = blockIdx.x, tid = threadIdx.x;
  const int m = mrow[row];
  const float* rp = acts + (size_t)row * FEAT;

  // pass 1: bits [31:21]
  for (int i = tid; i < 2048; i += 256) hist[i] = 0;
  __syncthreads();
  for (int i = tid; i < FEAT; i += 256){
    unsigned u = __float_as_uint(rp[i]);
    if (u) atomicAdd(&hist[u >> 21], 1);   // skip zeros (can never reach top-128)
  }
  __syncthreads();
  radix_find(hist, 2048, m, tid, out3, blksum);
  const int bin1 = out3[0];
  const int rem1 = out3[1];

  // collect candidates in bin1
  if (tid == 0) lcnt = 0;
  __syncthreads();
  for (int i = tid; i < FEAT; i += 256){
    unsigned u = __float_as_uint(rp[i]);
    if ((int)(u >> 21) == bin1){
      int p = atomicAdd(&lcnt, 1);
      if (p < 2048) listU[p] = u;
    }
  }
  __syncthreads();
  const int L = min(lcnt, 2048);

  // pass 2: bits [20:10]
  for (int i = tid; i < 2048; i += 256) hist[i] = 0;
  __syncthreads();
  for (int i = tid; i < L; i += 256) atomicAdd(&hist[(listU[i] >> 10) & 0x7FF], 1);
  __syncthreads();
  radix_find(hist, 2048, rem1, tid, out3, blksum);
  const int bin2 = out3[0];
  const int rem2 = out3[1];

  // pass 3: bits [9:0]
  for (int i = tid; i < 1024; i += 256) hist[i] = 0;
  __syncthreads();
  for (int i = tid; i < L; i += 256){
    unsigned u = listU[i];
    if ((int)((u >> 10) & 0x7FF) == bin2) atomicAdd(&hist[u & 0x3FF], 1);
  }
  __syncthreads();
  radix_find(hist, 1024, rem2, tid, out3, blksum);
  const int bin3 = out3[0];
  const int mEq  = out3[1];

  const unsigned tbits = ((unsigned)bin1 << 21) | ((unsigned)bin2 << 10) | (unsigned)bin3;

  // compaction: wave 0 only, deterministic index order
  if (tid < 64){
    const int base = row << 7;
    int cnt = 0;
    for (int c = 0; c < 256; ++c){
      const int i = (c << 6) + tid;
      const unsigned u = __float_as_uint(rp[i]);
      const bool g = (u > tbits);
      const unsigned long long mk = __ballot(g);
      if (g){
        int pos = cnt + __popcll(mk & ((1ull << tid) - 1ull));
        selIdx[base + pos] = i;
        selVal[base + pos] = __uint_as_float(u);
      }
      cnt += __popcll(mk);
    }
    int eqs = 0;
    for (int c = 0; c < 256 && eqs < mEq; ++c){
      const int i = (c << 6) + tid;
      const unsigned u = __float_as_uint(rp[i]);
      const bool e = (u == tbits);
      const unsigned long long mk = __ballot(e);
      if (e){
        int p = eqs + __popcll(mk & ((1ull << tid) - 1ull));
        if (p < mEq){
          selIdx[base + cnt + p] = i;
          selVal[base + cnt + p] = __uint_as_float(u);
        }
      }
      eqs += __popcll(mk);
    }
  }
}

// ---------------------------------------------------------------------------
// W_dec [DIM][FEAT] -> WdT [FEAT][DIM]
// ---------------------------------------------------------------------------
__global__ __launch_bounds__(256)
void transpose_dec(const float* __restrict__ Wd, float* __restrict__ WdT)
{
  __shared__ float t[64][65];
  const int f0 = blockIdx.x << 6, d0 = blockIdx.y << 6;
  const int tx = threadIdx.x & 15, ty = threadIdx.x >> 4;
  #pragma unroll
  for (int r = 0; r < 4; ++r){
    const int d = ty + (r << 4);
    const float4 v = *(const float4*)(Wd + (size_t)(d0 + d) * FEAT + f0 + (tx << 2));
    t[d][(tx << 2) + 0] = v.x;
    t[d][(tx << 2) + 1] = v.y;
    t[d][(tx << 2) + 2] = v.z;
    t[d][(tx << 2) + 3] = v.w;
  }
  __syncthreads();
  #pragma unroll
  for (int r = 0; r < 4; ++r){
    const int f = ty + (r << 4);
    float4 o;
    o.x = t[(tx << 2) + 0][f];
    o.y = t[(tx << 2) + 1][f];
    o.z = t[(tx << 2) + 2][f];
    o.w = t[(tx << 2) + 3][f];
    *(float4*)(WdT + (size_t)(f0 + f) * DIM + d0 + (tx << 2)) = o;
  }
}

// ---------------------------------------------------------------------------
// Sparse decode: out[row,:] = b_dec + sum_i selVal[i] * WdT[selIdx[i], :]
// ---------------------------------------------------------------------------
__global__ __launch_bounds__(256)
void decode_k(const float* __restrict__ WdT, const int* __restrict__ selIdx,
              const float* __restrict__ selVal, const int* __restrict__ mrow,
              const float* __restrict__ bdec, float* __restrict__ out)
{
  __shared__ int   sI[128];
  __shared__ float sV[128];
  const int row = blockIdx.x, tid = threadIdx.x;
  const int m = mrow[row];
  if (tid < m){
    sI[tid] = selIdx[(row << 7) + tid];
    sV[tid] = selVal[(row << 7) + tid];
  }
  __syncthreads();
  const int d = tid << 3;
  float a[8];
  {
    const float4 b0 = *(const float4*)(bdec + d);
    const float4 b1 = *(const float4*)(bdec + d + 4);
    a[0] = b0.x; a[1] = b0.y; a[2] = b0.z; a[3] = b0.w;
    a[4] = b1.x; a[5] = b1.y; a[6] = b1.z; a[7] = b1.w;
  }
  for (int i = 0; i < m; ++i){
    const float v = sV[i];
    const float* wp = WdT + (size_t)sI[i] * DIM + d;
    const float4 w0 = *(const float4*)wp;
    const float4 w1 = *(const float4*)(wp + 4);
    a[0] = fmaf(v, w0.x, a[0]); a[1] = fmaf(v, w0.y, a[1]);
    a[2] = fmaf(v, w0.z, a[2]); a[3] = fmaf(v, w0.w, a[3]);
    a[4] = fmaf(v, w1.x, a[4]); a[5] = fmaf(v, w1.y, a[5]);
    a[6] = fmaf(v, w1.z, a[6]); a[7] = fmaf(v, w1.w, a[7]);
  }
  float4 o0 = {a[0], a[1], a[2], a[3]};
  float4 o1 = {a[4], a[5], a[6], a[7]};
  *(float4*)(out + (size_t)row * DIM + d)     = o0;
  *(float4*)(out + (size_t)row * DIM + d + 4) = o1;
}

// ---------------------------------------------------------------------------
extern "C" void kernel_launch(void* const* d_in, const int* in_sizes, int n_in,
                              void* d_out, int out_size, void* d_ws, size_t ws_size,
                              hipStream_t stream)
{
  const float* x    = (const float*)d_in[0];
  const float* Wenc = (const float*)d_in[1];
  const float* benc = (const float*)d_in[2];
  const float* Wk1  = (const float*)d_in[3];
  const float* bk1  = (const float*)d_in[4];
  const float* Wk2  = (const float*)d_in[5];
  const float* bk2  = (const float*)d_in[6];
  const float* Wdec = (const float*)d_in[7];
  const float* bdec = (const float*)d_in[8];
  const int*   kp   = (const int*)d_in[9];
  float* out = (float*)d_out;

  char* ws = (char*)d_ws;
  const size_t ACTS_BYTES = (size_t)BATCH * FEAT * 4;   // 268435456
  float* acts   = (float*)ws;
  float* WdT    = (float*)ws;                           // aliased: used after select
  float* zpart  = (float*)(ws + ACTS_BYTES);            // 4096*256*4 = 4 MB
  int*   mrow   = (int*)  (ws + ACTS_BYTES + 4194304);  // 16 KB
  int*   selIdx = (int*)  (ws + ACTS_BYTES + 4194304 + 16384);           // 2 MB
  float* selVal = (float*)(ws + ACTS_BYTES + 4194304 + 16384 + 2097152); // 2 MB

  dim3 gg(FEAT / 128, BATCH / 128);
  gemm6<0><<<gg, dim3(256), 0, stream>>>(x, bdec, Wenc, benc, nullptr, acts, nullptr);
  gemm6<1><<<gg, dim3(256), 0, stream>>>(x, bdec, Wk1, bk1, Wk2, nullptr, zpart);
  zreduce<<<dim3(BATCH / 4), dim3(256), 0, stream>>>(zpart, bk2, kp, mrow);
  select_topk<<<dim3(BATCH), dim3(256), 0, stream>>>(acts, mrow, selIdx, selVal);
  transpose_dec<<<dim3(FEAT / 64, DIM / 64), dim3(256), 0, stream>>>(Wdec, WdT);
  decode_k<<<dim3(BATCH), dim3(256), 0, stream>>>(WdT, selIdx, selVal, mrow, bdec, out);
}